// Round 4
// baseline (1342.087 us; speedup 1.0000x reference)
//
#include <hip/hip_runtime.h>
#include <stdint.h>

typedef unsigned short u16;
typedef __attribute__((ext_vector_type(8))) short bf16x8;   // 8 bf16 = 4 VGPRs
typedef __attribute__((ext_vector_type(4))) float f32x4;

#define BATCH   4
#define CH      256
#define NPIX    4096      // 64*64
#define NGROUPS 32
#define CPG     8
#define EPS     1e-5f

// attention tiles
#define ATQ   32          // Q rows per block (2 waves x 16)
#define ATK   32          // KV rows per tile
#define NT    (NPIX / ATK)
#define KSTR  264         // K LDS row stride (elems): conflict-free
#define VSTR  40          // Vt LDS row stride
#define PSTR  40          // P LDS row stride

// ---------- bf16 helpers ----------
__device__ __forceinline__ float bf2f(u16 u) {
    union { uint32_t i; float f; } v; v.i = ((uint32_t)u) << 16; return v.f;
}
__device__ __forceinline__ u16 f2bf(float f) {
    union { float f; uint32_t i; } v; v.f = f;
    uint32_t x = v.i;
    uint32_t r = (x + 0x7fffu + ((x >> 16) & 1u)) >> 16;
    return (u16)r;
}
__device__ __forceinline__ void unpack2(uint32_t u, float& a, float& b) {
    union { uint32_t i; float f; } lo, hi;
    lo.i = u << 16; hi.i = u & 0xffff0000u;
    a = lo.f; b = hi.f;
}
__device__ __forceinline__ void unpack8(uint4 u, float* f) {
    unpack2(u.x, f[0], f[1]); unpack2(u.y, f[2], f[3]);
    unpack2(u.z, f[4], f[5]); unpack2(u.w, f[6], f[7]);
}

// ---------- runtime input-dtype detection (harness dtype unknown: fp32 vs bf16) ----------
__device__ __forceinline__ bool detect_f32(const void* xv) {
    const u16* p = (const u16*)xv;
    int bad = 0;
    #pragma unroll
    for (int i = 0; i < 32; i++) {
        u16 v = p[2 * i];
        int e = (v >> 7) & 0xff;
        bad += (e < 0x68 || e > 0x90) ? 1 : 0;
    }
    return bad >= 10;
}
__device__ __forceinline__ float load1(const void* b, size_t i, bool f32) {
    return f32 ? ((const float*)b)[i] : bf2f(((const u16*)b)[i]);
}
__device__ __forceinline__ void load4v(const void* base, size_t off, bool f32, float* f) {
    if (f32) {
        float4 a = *(const float4*)((const float*)base + off);
        f[0] = a.x; f[1] = a.y; f[2] = a.z; f[3] = a.w;
    } else {
        uint2 u = *(const uint2*)((const u16*)base + off);
        unpack2(u.x, f[0], f[1]); unpack2(u.y, f[2], f[3]);
    }
}
__device__ __forceinline__ void load8v(const void* base, size_t off, bool f32, float* f) {
    if (f32) {
        const float4* p = (const float4*)((const float*)base + off);
        float4 a = p[0], b = p[1];
        f[0] = a.x; f[1] = a.y; f[2] = a.z; f[3] = a.w;
        f[4] = b.x; f[5] = b.y; f[6] = b.z; f[7] = b.w;
    } else {
        uint4 u = *(const uint4*)((const u16*)base + off);
        unpack8(u, f);
    }
}
__device__ __forceinline__ void store4v(void* base, size_t off, bool f32, const float* f) {
    if (f32) {
        *(float4*)((float*)base + off) = make_float4(f[0], f[1], f[2], f[3]);
    } else {
        union { uint2 v; u16 s[4]; } pk;
        #pragma unroll
        for (int j = 0; j < 4; j++) pk.s[j] = f2bf(f[j]);
        *(uint2*)((u16*)base + off) = pk.v;
    }
}

// ---------- K1: GroupNorm stats ----------
__global__ __launch_bounds__(256) void gn_stats(const void* __restrict__ x,
                                                float* __restrict__ stats, int b0) {
    bool f32 = detect_f32(x);
    int bg = b0 * NGROUPS + blockIdx.x;
    int t  = threadIdx.x;
    size_t base = (size_t)bg * (CPG * NPIX);
    float s = 0.f, s2 = 0.f;
    for (int i = t * 8; i < CPG * NPIX; i += 256 * 8) {
        float f[8]; load8v(x, base + i, f32, f);
        #pragma unroll
        for (int e = 0; e < 8; e++) { s += f[e]; s2 += f[e] * f[e]; }
    }
    #pragma unroll
    for (int off = 1; off < 64; off <<= 1) {
        s  += __shfl_xor(s,  off);
        s2 += __shfl_xor(s2, off);
    }
    __shared__ float red[8];
    int w = t >> 6;
    if ((t & 63) == 0) { red[w * 2] = s; red[w * 2 + 1] = s2; }
    __syncthreads();
    if (t == 0) {
        float S  = red[0] + red[2] + red[4] + red[6];
        float S2 = red[1] + red[3] + red[5] + red[7];
        float n  = (float)(CPG * NPIX);
        float mu = S / n;
        float var = S2 / n - mu * mu;
        stats[bg * 2]     = mu;
        stats[bg * 2 + 1] = rsqrtf(var + EPS);
    }
}

// ---------- K2: fused GN-apply + QKV 1x1 conv ----------
// Q,K -> qk[bl][n][0..511]; V -> vt[bl][c][n] (pre-transposed for attention)
__global__ __launch_bounds__(256) void qkv_gemm(
    const void* __restrict__ x, const void* __restrict__ gn_w,
    const void* __restrict__ gn_b, const void* __restrict__ qkv_w,
    const void* __restrict__ qkv_b, const float* __restrict__ stats,
    u16* __restrict__ qk, u16* __restrict__ vt, int b0) {
    bool f32 = detect_f32(x);
    __shared__ float As[16][64];
    __shared__ float Ws[16][64];
    int bl = blockIdx.z, bg = b0 + bl;
    int n0 = blockIdx.x * 64, o0 = blockIdx.y * 64;
    int t  = threadIdx.x;
    int tx = t & 15, ty = t >> 4;
    float acc[4][4] = {};
    int lak = t >> 4, lan = (t & 15) * 4;
    int lwo = t >> 2, lwk = (t & 3) * 4;

    for (int k0 = 0; k0 < CH; k0 += 16) {
        int c = k0 + lak;
        int g = c >> 3;
        float mu = stats[(bg * NGROUPS + g) * 2];
        float rs = stats[(bg * NGROUPS + g) * 2 + 1];
        float wv = load1(gn_w, c, f32) * rs;
        float bv = load1(gn_b, c, f32) - mu * wv;
        float a[4];
        load4v(x, ((size_t)(bg * CH + c)) * NPIX + n0 + lan, f32, a);
        As[lak][lan + 0] = a[0] * wv + bv;
        As[lak][lan + 1] = a[1] * wv + bv;
        As[lak][lan + 2] = a[2] * wv + bv;
        As[lak][lan + 3] = a[3] * wv + bv;

        float wf[4];
        load4v(qkv_w, (size_t)(o0 + lwo) * CH + k0 + lwk, f32, wf);
        Ws[lwk + 0][lwo] = wf[0]; Ws[lwk + 1][lwo] = wf[1];
        Ws[lwk + 2][lwo] = wf[2]; Ws[lwk + 3][lwo] = wf[3];
        __syncthreads();
        #pragma unroll
        for (int kk = 0; kk < 16; kk++) {
            float4 av = *(const float4*)&As[kk][tx * 4];
            float4 wv4 = *(const float4*)&Ws[kk][ty * 4];
            float aa[4] = {av.x, av.y, av.z, av.w};
            float ww[4] = {wv4.x, wv4.y, wv4.z, wv4.w};
            #pragma unroll
            for (int i = 0; i < 4; i++)
                #pragma unroll
                for (int j = 0; j < 4; j++)
                    acc[i][j] = fmaf(aa[i], ww[j], acc[i][j]);
        }
        __syncthreads();
    }
    float bias[4];
    #pragma unroll
    for (int j = 0; j < 4; j++) bias[j] = load1(qkv_b, o0 + ty * 4 + j, f32);
    if (o0 < 512) {
        #pragma unroll
        for (int i = 0; i < 4; i++) {
            union { uint2 v; u16 s[4]; } pk;
            #pragma unroll
            for (int j = 0; j < 4; j++) pk.s[j] = f2bf(acc[i][j] + bias[j]);
            *(uint2*)(qk + ((size_t)(bl * NPIX + n0 + tx * 4 + i)) * 512 + o0 + ty * 4) = pk.v;
        }
    } else {
        int c0 = o0 - 512 + ty * 4;
        #pragma unroll
        for (int j = 0; j < 4; j++) {
            union { uint2 v; u16 s[4]; } pk;
            #pragma unroll
            for (int i = 0; i < 4; i++) pk.s[i] = f2bf(acc[i][j] + bias[j]);
            *(uint2*)(vt + ((size_t)(bl * CH + c0 + j)) * NPIX + n0 + tx * 4) = pk.v;
        }
    }
}

// ---------- K3: MFMA flash attention, pipelined double-buffered staging ----------
// No-max softmax: S=(q.k)/16 has |S|<~2 (bounded inputs), so p=exp(S) is safe
// in fp32 without running max; l accumulated per-lane, reduced once at end.
__global__ __launch_bounds__(128, 1) void attn_mfma(const u16* __restrict__ qk,
                                                    const u16* __restrict__ vt,
                                                    u16* __restrict__ attO) {
    __shared__ u16 Ks[2][ATK * KSTR];    // 2 x 16.5 KB
    __shared__ u16 Vts[2][CH * VSTR];    // 2 x 20 KB
    __shared__ u16 Ps[2][16 * PSTR];     // per-wave P roundtrip
    int bl   = blockIdx.y;
    int q0   = blockIdx.x * ATQ;
    int t    = threadIdx.x;
    int w    = t >> 6;
    int lane = t & 63;
    int l15  = lane & 15;
    int quad = lane >> 4;

    const u16* qkb = qk + (size_t)bl * NPIX * 512;
    const u16* vtb = vt + (size_t)bl * CH * NPIX;

    // Q fragments: A[m=l15][k=kc*32+quad*8+j]
    bf16x8 qf[8];
    {
        const u16* qrow = qkb + (size_t)(q0 + 16 * w + l15) * 512;
        #pragma unroll
        for (int kc = 0; kc < 8; kc++)
            qf[kc] = *(const bf16x8*)(qrow + kc * 32 + quad * 8);
    }
    f32x4 o[16];
    #pragma unroll
    for (int i = 0; i < 16; i++) o[i] = (f32x4){0.f, 0.f, 0.f, 0.f};
    float lsum[4] = {0.f, 0.f, 0.f, 0.f};
    const float scale = 0.0625f;

    uint4 kreg[8], vreg[8];
    // prologue: stage tile 0 into buffer 0
    #pragma unroll
    for (int i = 0; i < 8; i++) {
        int e = t + i * 128;
        kreg[i] = *(const uint4*)(qkb + (size_t)(e >> 5) * 512 + 256 + (e & 31) * 8);
        vreg[i] = *(const uint4*)(vtb + (size_t)(e >> 2) * NPIX + (e & 3) * 8);
    }
    #pragma unroll
    for (int i = 0; i < 8; i++) {
        int e = t + i * 128;
        *(uint4*)(&Ks[0][(e >> 5) * KSTR + (e & 31) * 8]) = kreg[i];
        *(uint4*)(&Vts[0][(e >> 2) * VSTR + (e & 3) * 8]) = vreg[i];
    }
    __syncthreads();

    for (int it = 0; it < NT; it++) {
        int cur = it & 1;
        // issue next tile's global loads (overlap with compute below)
        if (it + 1 < NT) {
            int kvn = (it + 1) * ATK;
            #pragma unroll
            for (int i = 0; i < 8; i++) {
                int e = t + i * 128;
                kreg[i] = *(const uint4*)(qkb + (size_t)(kvn + (e >> 5)) * 512 + 256 + (e & 31) * 8);
                vreg[i] = *(const uint4*)(vtb + (size_t)(e >> 2) * NPIX + kvn + (e & 3) * 8);
            }
        }

        // S = Q.K^T (two 16x16 tiles)
        const u16* Kb = Ks[cur];
        const u16* Vb = Vts[cur];
        f32x4 s0 = (f32x4){0.f, 0.f, 0.f, 0.f};
        f32x4 s1 = (f32x4){0.f, 0.f, 0.f, 0.f};
        #pragma unroll
        for (int kc = 0; kc < 8; kc++) {
            bf16x8 b0 = *(const bf16x8*)(Kb + l15 * KSTR + kc * 32 + quad * 8);
            bf16x8 b1 = *(const bf16x8*)(Kb + (16 + l15) * KSTR + kc * 32 + quad * 8);
            s0 = __builtin_amdgcn_mfma_f32_16x16x32_bf16(qf[kc], b0, s0, 0, 0, 0);
            s1 = __builtin_amdgcn_mfma_f32_16x16x32_bf16(qf[kc], b1, s1, 0, 0, 0);
        }

        // p = exp(s/16), no max subtraction; accumulate per-lane l
        #pragma unroll
        for (int r = 0; r < 4; r++) {
            float p0 = __expf(s0[r] * scale);
            float p1 = __expf(s1[r] * scale);
            lsum[r] += p0 + p1;
            Ps[w][(quad * 4 + r) * PSTR + l15]      = f2bf(p0);
            Ps[w][(quad * 4 + r) * PSTR + 16 + l15] = f2bf(p1);
        }

        // PV: A = P (A-layout read, wave-private), B = V^T rows
        bf16x8 pf = *(const bf16x8*)(&Ps[w][l15 * PSTR + quad * 8]);
        #pragma unroll
        for (int dt = 0; dt < 16; dt++) {
            bf16x8 vf = *(const bf16x8*)(Vb + (dt * 16 + l15) * VSTR + quad * 8);
            o[dt] = __builtin_amdgcn_mfma_f32_16x16x32_bf16(pf, vf, o[dt], 0, 0, 0);
        }

        // commit staged regs into the other buffer
        if (it + 1 < NT) {
            int nb = (it + 1) & 1;
            #pragma unroll
            for (int i = 0; i < 8; i++) {
                int e = t + i * 128;
                *(uint4*)(&Ks[nb][(e >> 5) * KSTR + (e & 31) * 8]) = kreg[i];
                *(uint4*)(&Vts[nb][(e >> 2) * VSTR + (e & 3) * 8]) = vreg[i];
            }
        }
        __syncthreads();
    }

    // one-time l reduction across the 16 lanes of each C-layout row group
    float inv[4];
    #pragma unroll
    for (int r = 0; r < 4; r++) {
        float v = lsum[r];
        v += __shfl_xor(v, 1); v += __shfl_xor(v, 2);
        v += __shfl_xor(v, 4); v += __shfl_xor(v, 8);
        inv[r] = 1.0f / v;
    }
    u16* ob = attO + ((size_t)(bl * NPIX + q0 + 16 * w)) * CH;
    #pragma unroll
    for (int dt = 0; dt < 16; dt++)
        #pragma unroll
        for (int r = 0; r < 4; r++)
            ob[(quad * 4 + r) * CH + dt * 16 + l15] = f2bf(o[dt][r] * inv[r]);
}

// ---------- K4: proj 1x1 conv + residual ----------
__global__ __launch_bounds__(256) void proj_gemm(
    const u16* __restrict__ attO, const void* __restrict__ proj_w,
    const void* __restrict__ proj_b, const void* __restrict__ x,
    void* __restrict__ out, int b0) {
    bool f32 = detect_f32(x);
    __shared__ float As[16][68];
    __shared__ float Ws[16][64];
    int bl = blockIdx.z, bg = b0 + bl;
    int n0 = blockIdx.x * 64, o0 = blockIdx.y * 64;
    int t  = threadIdx.x;
    int tx = t & 15, ty = t >> 4;
    float acc[4][4] = {};
    int lan2 = t >> 2, lak2 = (t & 3) * 4;
    int lwo = t >> 2,  lwk = (t & 3) * 4;

    for (int k0 = 0; k0 < CH; k0 += 16) {
        uint2 u = *(const uint2*)(attO + ((size_t)(bl * NPIX + n0 + lan2)) * CH + k0 + lak2);
        float a0, a1, a2, a3; unpack2(u.x, a0, a1); unpack2(u.y, a2, a3);
        As[lak2 + 0][lan2] = a0; As[lak2 + 1][lan2] = a1;
        As[lak2 + 2][lan2] = a2; As[lak2 + 3][lan2] = a3;

        float wf[4];
        load4v(proj_w, (size_t)(o0 + lwo) * CH + k0 + lwk, f32, wf);
        Ws[lwk + 0][lwo] = wf[0]; Ws[lwk + 1][lwo] = wf[1];
        Ws[lwk + 2][lwo] = wf[2]; Ws[lwk + 3][lwo] = wf[3];
        __syncthreads();
        #pragma unroll
        for (int kk = 0; kk < 16; kk++) {
            float4 av = *(const float4*)&As[kk][tx * 4];
            float4 wv4 = *(const float4*)&Ws[kk][ty * 4];
            float aa[4] = {av.x, av.y, av.z, av.w};
            float ww[4] = {wv4.x, wv4.y, wv4.z, wv4.w};
            #pragma unroll
            for (int i = 0; i < 4; i++)
                #pragma unroll
                for (int j = 0; j < 4; j++)
                    acc[i][j] = fmaf(aa[i], ww[j], acc[i][j]);
        }
        __syncthreads();
    }
    #pragma unroll
    for (int j = 0; j < 4; j++) {
        float bias = load1(proj_b, o0 + ty * 4 + j, f32);
        size_t off = ((size_t)(bg * CH + o0 + ty * 4 + j)) * NPIX + n0 + tx * 4;
        float rx[4];
        load4v(x, off, f32, rx);
        float fo[4];
        #pragma unroll
        for (int i = 0; i < 4; i++) fo[i] = acc[i][j] + bias + rx[i];
        store4v(out, off, f32, fo);
    }
}

extern "C" void kernel_launch(void* const* d_in, const int* in_sizes, int n_in,
                              void* d_out, int out_size, void* d_ws, size_t ws_size,
                              hipStream_t stream) {
    const void* x      = d_in[0];
    const void* gn_w   = d_in[1];
    const void* gn_b   = d_in[2];
    const void* qkv_w  = d_in[3];
    const void* qkv_b  = d_in[4];
    const void* proj_w = d_in[5];
    const void* proj_b = d_in[6];

    char* ws = (char*)d_ws;
    float* stats = (float*)ws;
    const size_t per_batch = (size_t)NPIX * 512 * 2 + (size_t)CH * NPIX * 2 + (size_t)NPIX * CH * 2;
    const size_t need_full = 1024 + BATCH * per_batch;   // 33.56 MB (ws is ~268 MB)
    int nb = (ws_size >= need_full) ? BATCH : 1;

    u16* qk   = (u16*)(ws + 1024);
    u16* vt   = qk + (size_t)nb * NPIX * 512;
    u16* attO = vt + (size_t)nb * CH * NPIX;

    for (int b0 = 0; b0 < BATCH; b0 += nb) {
        gn_stats<<<dim3(nb * NGROUPS), 256, 0, stream>>>(x, stats, b0);
        qkv_gemm<<<dim3(NPIX / 64, 768 / 64, nb), 256, 0, stream>>>(
            x, gn_w, gn_b, qkv_w, qkv_b, stats, qk, vt, b0);
        attn_mfma<<<dim3(NPIX / ATQ, nb), 128, 0, stream>>>(qk, vt, attO);
        proj_gemm<<<dim3(NPIX / 64, CH / 64, nb), 256, 0, stream>>>(
            attO, proj_w, proj_b, x, d_out, b0);
    }
}

// Round 5
// 391.033 us; speedup vs baseline: 3.4322x; 3.4322x over previous
//
#include <hip/hip_runtime.h>
#include <stdint.h>

typedef unsigned short u16;
typedef __attribute__((ext_vector_type(8))) short bf16x8;   // 8 bf16 = 4 VGPRs
typedef __attribute__((ext_vector_type(4))) float f32x4;

#define BATCH   4
#define CH      256
#define NPIX    4096      // 64*64
#define NGROUPS 32
#define CPG     8
#define EPS     1e-5f

// attention tiles
#define ATQ    32         // Q rows per block (2 waves x 16)
#define ATK    32         // KV rows per tile
#define NSPLIT 4          // KV-range split (exact: no-max softmax partials are pure sums)
#define SPLEN  (NPIX / NSPLIT)   // 1024 kv rows per split
#define NIT    (SPLEN / ATK)     // 32 iters
#define KSTR  264         // K LDS row stride (elems): conflict-free
#define VSTR  40          // Vt LDS row stride
#define PSTR  40          // P LDS row stride

// ---------- bf16 helpers ----------
__device__ __forceinline__ float bf2f(u16 u) {
    union { uint32_t i; float f; } v; v.i = ((uint32_t)u) << 16; return v.f;
}
__device__ __forceinline__ u16 f2bf(float f) {
    union { float f; uint32_t i; } v; v.f = f;
    uint32_t x = v.i;
    uint32_t r = (x + 0x7fffu + ((x >> 16) & 1u)) >> 16;
    return (u16)r;
}
__device__ __forceinline__ void unpack2(uint32_t u, float& a, float& b) {
    union { uint32_t i; float f; } lo, hi;
    lo.i = u << 16; hi.i = u & 0xffff0000u;
    a = lo.f; b = hi.f;
}
__device__ __forceinline__ void unpack8(uint4 u, float* f) {
    unpack2(u.x, f[0], f[1]); unpack2(u.y, f[2], f[3]);
    unpack2(u.z, f[4], f[5]); unpack2(u.w, f[6], f[7]);
}

// ---------- runtime input-dtype detection (harness dtype unknown: fp32 vs bf16) ----------
__device__ __forceinline__ bool detect_f32(const void* xv) {
    const u16* p = (const u16*)xv;
    int bad = 0;
    #pragma unroll
    for (int i = 0; i < 32; i++) {
        u16 v = p[2 * i];
        int e = (v >> 7) & 0xff;
        bad += (e < 0x68 || e > 0x90) ? 1 : 0;
    }
    return bad >= 10;
}
__device__ __forceinline__ float load1(const void* b, size_t i, bool f32) {
    return f32 ? ((const float*)b)[i] : bf2f(((const u16*)b)[i]);
}
__device__ __forceinline__ void load4v(const void* base, size_t off, bool f32, float* f) {
    if (f32) {
        float4 a = *(const float4*)((const float*)base + off);
        f[0] = a.x; f[1] = a.y; f[2] = a.z; f[3] = a.w;
    } else {
        uint2 u = *(const uint2*)((const u16*)base + off);
        unpack2(u.x, f[0], f[1]); unpack2(u.y, f[2], f[3]);
    }
}
__device__ __forceinline__ void load8v(const void* base, size_t off, bool f32, float* f) {
    if (f32) {
        const float4* p = (const float4*)((const float*)base + off);
        float4 a = p[0], b = p[1];
        f[0] = a.x; f[1] = a.y; f[2] = a.z; f[3] = a.w;
        f[4] = b.x; f[5] = b.y; f[6] = b.z; f[7] = b.w;
    } else {
        uint4 u = *(const uint4*)((const u16*)base + off);
        unpack8(u, f);
    }
}
__device__ __forceinline__ void store4v(void* base, size_t off, bool f32, const float* f) {
    if (f32) {
        *(float4*)((float*)base + off) = make_float4(f[0], f[1], f[2], f[3]);
    } else {
        union { uint2 v; u16 s[4]; } pk;
        #pragma unroll
        for (int j = 0; j < 4; j++) pk.s[j] = f2bf(f[j]);
        *(uint2*)((u16*)base + off) = pk.v;
    }
}

// ---------- K1: GroupNorm stats ----------
__global__ __launch_bounds__(256) void gn_stats(const void* __restrict__ x,
                                                float* __restrict__ stats, int b0) {
    bool f32 = detect_f32(x);
    int bg = b0 * NGROUPS + blockIdx.x;
    int t  = threadIdx.x;
    size_t base = (size_t)bg * (CPG * NPIX);
    float s = 0.f, s2 = 0.f;
    for (int i = t * 8; i < CPG * NPIX; i += 256 * 8) {
        float f[8]; load8v(x, base + i, f32, f);
        #pragma unroll
        for (int e = 0; e < 8; e++) { s += f[e]; s2 += f[e] * f[e]; }
    }
    #pragma unroll
    for (int off = 1; off < 64; off <<= 1) {
        s  += __shfl_xor(s,  off);
        s2 += __shfl_xor(s2, off);
    }
    __shared__ float red[8];
    int w = t >> 6;
    if ((t & 63) == 0) { red[w * 2] = s; red[w * 2 + 1] = s2; }
    __syncthreads();
    if (t == 0) {
        float S  = red[0] + red[2] + red[4] + red[6];
        float S2 = red[1] + red[3] + red[5] + red[7];
        float n  = (float)(CPG * NPIX);
        float mu = S / n;
        float var = S2 / n - mu * mu;
        stats[bg * 2]     = mu;
        stats[bg * 2 + 1] = rsqrtf(var + EPS);
    }
}

// ---------- K2: fused GN-apply + QKV 1x1 conv ----------
// Q,K -> qk[bl][n][0..511]; V -> vt[bl][c][n] (pre-transposed for attention)
__global__ __launch_bounds__(256) void qkv_gemm(
    const void* __restrict__ x, const void* __restrict__ gn_w,
    const void* __restrict__ gn_b, const void* __restrict__ qkv_w,
    const void* __restrict__ qkv_b, const float* __restrict__ stats,
    u16* __restrict__ qk, u16* __restrict__ vt, int b0) {
    bool f32 = detect_f32(x);
    __shared__ float As[16][64];
    __shared__ float Ws[16][64];
    int bl = blockIdx.z, bg = b0 + bl;
    int n0 = blockIdx.x * 64, o0 = blockIdx.y * 64;
    int t  = threadIdx.x;
    int tx = t & 15, ty = t >> 4;
    float acc[4][4] = {};
    int lak = t >> 4, lan = (t & 15) * 4;
    int lwo = t >> 2, lwk = (t & 3) * 4;

    for (int k0 = 0; k0 < CH; k0 += 16) {
        int c = k0 + lak;
        int g = c >> 3;
        float mu = stats[(bg * NGROUPS + g) * 2];
        float rs = stats[(bg * NGROUPS + g) * 2 + 1];
        float wv = load1(gn_w, c, f32) * rs;
        float bv = load1(gn_b, c, f32) - mu * wv;
        float a[4];
        load4v(x, ((size_t)(bg * CH + c)) * NPIX + n0 + lan, f32, a);
        As[lak][lan + 0] = a[0] * wv + bv;
        As[lak][lan + 1] = a[1] * wv + bv;
        As[lak][lan + 2] = a[2] * wv + bv;
        As[lak][lan + 3] = a[3] * wv + bv;

        float wf[4];
        load4v(qkv_w, (size_t)(o0 + lwo) * CH + k0 + lwk, f32, wf);
        Ws[lwk + 0][lwo] = wf[0]; Ws[lwk + 1][lwo] = wf[1];
        Ws[lwk + 2][lwo] = wf[2]; Ws[lwk + 3][lwo] = wf[3];
        __syncthreads();
        #pragma unroll
        for (int kk = 0; kk < 16; kk++) {
            float4 av = *(const float4*)&As[kk][tx * 4];
            float4 wv4 = *(const float4*)&Ws[kk][ty * 4];
            float aa[4] = {av.x, av.y, av.z, av.w};
            float ww[4] = {wv4.x, wv4.y, wv4.z, wv4.w};
            #pragma unroll
            for (int i = 0; i < 4; i++)
                #pragma unroll
                for (int j = 0; j < 4; j++)
                    acc[i][j] = fmaf(aa[i], ww[j], acc[i][j]);
        }
        __syncthreads();
    }
    float bias[4];
    #pragma unroll
    for (int j = 0; j < 4; j++) bias[j] = load1(qkv_b, o0 + ty * 4 + j, f32);
    if (o0 < 512) {
        #pragma unroll
        for (int i = 0; i < 4; i++) {
            union { uint2 v; u16 s[4]; } pk;
            #pragma unroll
            for (int j = 0; j < 4; j++) pk.s[j] = f2bf(acc[i][j] + bias[j]);
            *(uint2*)(qk + ((size_t)(bl * NPIX + n0 + tx * 4 + i)) * 512 + o0 + ty * 4) = pk.v;
        }
    } else {
        int c0 = o0 - 512 + ty * 4;
        #pragma unroll
        for (int j = 0; j < 4; j++) {
            union { uint2 v; u16 s[4]; } pk;
            #pragma unroll
            for (int i = 0; i < 4; i++) pk.s[i] = f2bf(acc[i][j] + bias[j]);
            *(uint2*)(vt + ((size_t)(bl * CH + c0 + j)) * NPIX + n0 + tx * 4) = pk.v;
        }
    }
}

// ---------- K3: MFMA flash attention, KV-split for occupancy ----------
// grid (NPIX/ATQ, NSPLIT, nb). Each block handles 1024 kv rows; partial
// unnormalized O (fp32) and partial l written to ws; combined exactly later
// (no-max softmax => partials are pure sums). R3 structure otherwise
// (register double-buffer removed: it spilled to scratch, 1 GB/dispatch).
__global__ __launch_bounds__(128, 2) void attn_mfma(const u16* __restrict__ qk,
                                                    const u16* __restrict__ vt,
                                                    float* __restrict__ Opart,
                                                    float* __restrict__ lpart,
                                                    int NE, int NR) {
    __shared__ u16 Ks[ATK * KSTR];       // 16.5 KB
    __shared__ u16 Vts[CH * VSTR];       // 20 KB
    __shared__ u16 Ps[2][16 * PSTR];     // per-wave P roundtrip
    int bl    = blockIdx.z;
    int split = blockIdx.y;
    int q0    = blockIdx.x * ATQ;
    int t     = threadIdx.x;
    int w     = t >> 6;
    int lane  = t & 63;
    int l15   = lane & 15;
    int quad  = lane >> 4;

    const u16* qkb = qk + (size_t)bl * NPIX * 512;
    const u16* vtb = vt + (size_t)bl * CH * NPIX;
    int kvbase = split * SPLEN;

    // Q fragments: A[m=l15][k=kc*32+quad*8+j]
    bf16x8 qf[8];
    {
        const u16* qrow = qkb + (size_t)(q0 + 16 * w + l15) * 512;
        #pragma unroll
        for (int kc = 0; kc < 8; kc++)
            qf[kc] = *(const bf16x8*)(qrow + kc * 32 + quad * 8);
    }
    f32x4 o[16];
    #pragma unroll
    for (int i = 0; i < 16; i++) o[i] = (f32x4){0.f, 0.f, 0.f, 0.f};
    float lsum[4] = {0.f, 0.f, 0.f, 0.f};
    const float scale = 0.0625f;

    for (int it = 0; it < NIT; it++) {
        int kv0 = kvbase + it * ATK;
        __syncthreads();   // prev-iter LDS reads done
        #pragma unroll
        for (int i = 0; i < 8; i++) {
            int e = t + i * 128;
            int row = e >> 5, ch = e & 31;
            *(uint4*)(Ks + row * KSTR + ch * 8) =
                *(const uint4*)(qkb + (size_t)(kv0 + row) * 512 + 256 + ch * 8);
        }
        #pragma unroll
        for (int i = 0; i < 8; i++) {
            int e = t + i * 128;
            int row = e >> 2, ch = e & 3;
            *(uint4*)(Vts + row * VSTR + ch * 8) =
                *(const uint4*)(vtb + (size_t)row * NPIX + kv0 + ch * 8);
        }
        __syncthreads();

        // S = Q.K^T (two 16x16 tiles)
        f32x4 s0 = (f32x4){0.f, 0.f, 0.f, 0.f};
        f32x4 s1 = (f32x4){0.f, 0.f, 0.f, 0.f};
        #pragma unroll
        for (int kc = 0; kc < 8; kc++) {
            bf16x8 b0 = *(const bf16x8*)(Ks + l15 * KSTR + kc * 32 + quad * 8);
            bf16x8 b1 = *(const bf16x8*)(Ks + (16 + l15) * KSTR + kc * 32 + quad * 8);
            s0 = __builtin_amdgcn_mfma_f32_16x16x32_bf16(qf[kc], b0, s0, 0, 0, 0);
            s1 = __builtin_amdgcn_mfma_f32_16x16x32_bf16(qf[kc], b1, s1, 0, 0, 0);
        }

        // p = exp(s/16), no max subtraction (|S|<~2 for N(0,1)-scale inputs)
        #pragma unroll
        for (int r = 0; r < 4; r++) {
            float p0 = __expf(s0[r] * scale);
            float p1 = __expf(s1[r] * scale);
            lsum[r] += p0 + p1;
            Ps[w][(quad * 4 + r) * PSTR + l15]      = f2bf(p0);
            Ps[w][(quad * 4 + r) * PSTR + 16 + l15] = f2bf(p1);
        }

        // PV: A = P (A-layout read, wave-private), B = V^T rows
        bf16x8 pf = *(const bf16x8*)(&Ps[w][l15 * PSTR + quad * 8]);
        #pragma unroll
        for (int dt = 0; dt < 16; dt++) {
            bf16x8 vf = *(const bf16x8*)(Vts + (dt * 16 + l15) * VSTR + quad * 8);
            o[dt] = __builtin_amdgcn_mfma_f32_16x16x32_bf16(pf, vf, o[dt], 0, 0, 0);
        }
    }

    // reduce per-lane l over the 16 lanes of each C-layout row; write partials
    float lred[4];
    #pragma unroll
    for (int r = 0; r < 4; r++) {
        float v = lsum[r];
        v += __shfl_xor(v, 1); v += __shfl_xor(v, 2);
        v += __shfl_xor(v, 4); v += __shfl_xor(v, 8);
        lred[r] = v;
    }
    size_t rowb = (size_t)bl * NPIX + q0 + 16 * w;
    float* op = Opart + (size_t)split * NE;
    #pragma unroll
    for (int r = 0; r < 4; r++)
        if (l15 == 0) lpart[(size_t)split * NR + rowb + quad * 4 + r] = lred[r];
    #pragma unroll
    for (int dt = 0; dt < 16; dt++)
        #pragma unroll
        for (int r = 0; r < 4; r++)
            op[(rowb + quad * 4 + r) * CH + dt * 16 + l15] = o[dt][r];
}

// ---------- K3b: combine KV-split partials -> attO bf16 ----------
__global__ __launch_bounds__(256) void attn_combine(const float* __restrict__ Opart,
                                                    const float* __restrict__ lpart,
                                                    u16* __restrict__ attO,
                                                    int NE, int NR) {
    int idx4 = (blockIdx.x * 256 + threadIdx.x) * 4;
    if (idx4 >= NE) return;
    int row = idx4 >> 8;
    float l = lpart[row] + lpart[NR + row] + lpart[2 * NR + row] + lpart[3 * NR + row];
    float4 a = *(const float4*)(Opart + idx4);
    float4 b = *(const float4*)(Opart + (size_t)NE + idx4);
    float4 c = *(const float4*)(Opart + 2 * (size_t)NE + idx4);
    float4 d = *(const float4*)(Opart + 3 * (size_t)NE + idx4);
    float inv = 1.0f / l;
    union { uint2 v; u16 s[4]; } pk;
    pk.s[0] = f2bf((a.x + b.x + c.x + d.x) * inv);
    pk.s[1] = f2bf((a.y + b.y + c.y + d.y) * inv);
    pk.s[2] = f2bf((a.z + b.z + c.z + d.z) * inv);
    pk.s[3] = f2bf((a.w + b.w + c.w + d.w) * inv);
    *(uint2*)(attO + idx4) = pk.v;
}

// ---------- K4: proj 1x1 conv + residual ----------
__global__ __launch_bounds__(256) void proj_gemm(
    const u16* __restrict__ attO, const void* __restrict__ proj_w,
    const void* __restrict__ proj_b, const void* __restrict__ x,
    void* __restrict__ out, int b0) {
    bool f32 = detect_f32(x);
    __shared__ float As[16][68];
    __shared__ float Ws[16][64];
    int bl = blockIdx.z, bg = b0 + bl;
    int n0 = blockIdx.x * 64, o0 = blockIdx.y * 64;
    int t  = threadIdx.x;
    int tx = t & 15, ty = t >> 4;
    float acc[4][4] = {};
    int lan2 = t >> 2, lak2 = (t & 3) * 4;
    int lwo = t >> 2,  lwk = (t & 3) * 4;

    for (int k0 = 0; k0 < CH; k0 += 16) {
        uint2 u = *(const uint2*)(attO + ((size_t)(bl * NPIX + n0 + lan2)) * CH + k0 + lak2);
        float a0, a1, a2, a3; unpack2(u.x, a0, a1); unpack2(u.y, a2, a3);
        As[lak2 + 0][lan2] = a0; As[lak2 + 1][lan2] = a1;
        As[lak2 + 2][lan2] = a2; As[lak2 + 3][lan2] = a3;

        float wf[4];
        load4v(proj_w, (size_t)(o0 + lwo) * CH + k0 + lwk, f32, wf);
        Ws[lwk + 0][lwo] = wf[0]; Ws[lwk + 1][lwo] = wf[1];
        Ws[lwk + 2][lwo] = wf[2]; Ws[lwk + 3][lwo] = wf[3];
        __syncthreads();
        #pragma unroll
        for (int kk = 0; kk < 16; kk++) {
            float4 av = *(const float4*)&As[kk][tx * 4];
            float4 wv4 = *(const float4*)&Ws[kk][ty * 4];
            float aa[4] = {av.x, av.y, av.z, av.w};
            float ww[4] = {wv4.x, wv4.y, wv4.z, wv4.w};
            #pragma unroll
            for (int i = 0; i < 4; i++)
                #pragma unroll
                for (int j = 0; j < 4; j++)
                    acc[i][j] = fmaf(aa[i], ww[j], acc[i][j]);
        }
        __syncthreads();
    }
    #pragma unroll
    for (int j = 0; j < 4; j++) {
        float bias = load1(proj_b, o0 + ty * 4 + j, f32);
        size_t off = ((size_t)(bg * CH + o0 + ty * 4 + j)) * NPIX + n0 + tx * 4;
        float rx[4];
        load4v(x, off, f32, rx);
        float fo[4];
        #pragma unroll
        for (int i = 0; i < 4; i++) fo[i] = acc[i][j] + bias + rx[i];
        store4v(out, off, f32, fo);
    }
}

extern "C" void kernel_launch(void* const* d_in, const int* in_sizes, int n_in,
                              void* d_out, int out_size, void* d_ws, size_t ws_size,
                              hipStream_t stream) {
    const void* x      = d_in[0];
    const void* gn_w   = d_in[1];
    const void* gn_b   = d_in[2];
    const void* qkv_w  = d_in[3];
    const void* qkv_b  = d_in[4];
    const void* proj_w = d_in[5];
    const void* proj_b = d_in[6];

    char* ws = (char*)d_ws;
    float* stats = (float*)ws;
    // per batch: qk 4 MB + vt 2 MB + attO 2 MB + Opart 16 MB + lpart 64 KB
    const size_t per_batch = (size_t)NPIX * 512 * 2 + (size_t)CH * NPIX * 2 +
                             (size_t)NPIX * CH * 2 +
                             (size_t)NSPLIT * NPIX * CH * 4 + (size_t)NSPLIT * NPIX * 4;
    const size_t need_full = 1024 + BATCH * per_batch;   // ~101 MB (ws ~268 MB)
    int nb = (ws_size >= need_full) ? BATCH : 1;

    u16* qk      = (u16*)(ws + 1024);
    u16* vt      = qk + (size_t)nb * NPIX * 512;
    u16* attO    = vt + (size_t)nb * CH * NPIX;
    float* Opart = (float*)(attO + (size_t)nb * NPIX * CH);
    float* lpart = Opart + (size_t)NSPLIT * nb * NPIX * CH;
    int NE = nb * NPIX * CH;      // elems per split in Opart
    int NR = nb * NPIX;           // rows per split in lpart

    for (int b0 = 0; b0 < BATCH; b0 += nb) {
        gn_stats<<<dim3(nb * NGROUPS), 256, 0, stream>>>(x, stats, b0);
        qkv_gemm<<<dim3(NPIX / 64, 768 / 64, nb), 256, 0, stream>>>(
            x, gn_w, gn_b, qkv_w, qkv_b, stats, qk, vt, b0);
        attn_mfma<<<dim3(NPIX / ATQ, NSPLIT, nb), 128, 0, stream>>>(
            qk, vt, Opart, lpart, NE, NR);
        attn_combine<<<dim3(NE / 1024), 256, 0, stream>>>(Opart, lpart, attO, NE, NR);
        proj_gemm<<<dim3(NPIX / 64, CH / 64, nb), 256, 0, stream>>>(
            attO, proj_w, proj_b, x, d_out, b0);
    }
}